// Round 6
// baseline (103.266 us; speedup 1.0000x reference)
//
#include <hip/hip_runtime.h>

// ============================================================================
// AttenPool: softmax-over-L summed over L == 1, so
//   out[b,c,P] = (1-a)*( sumpool4(conv3(BN(x),wv))[c,P] + 16*bv[c] )
//                + a*sumpool4(x)[c,P]
// sumpool4 o conv3 == 6x6 stride-4 conv (W6); BN scale folds into W6; BN offset
// -> per-(outch, border-class) constant (9 classes). The per-channel a*x
// patch-sum is ALSO a 6x6 stride-4 conv (weight a*delta_{o,i}, interior taps)
// -> folded into the same weight table.
// Conv = implicit GEMM on mfma_f32_16x16x32_bf16; A and B fragments use the
// IDENTICAL (lane-group, elem)->(tap, channel) map so any internal HW
// k-permutation cancels. LDS x tile [pixel][16ch] bf16, double-buffered,
// bijective swizzle addr = (p*32+hh*16) ^ (((p>>2)&7)<<4).
// Round 6: tile 32x32 px -> 16x32 px (grid 256->512, 1->2 blocks/CU) to fix
// the latency-bound profile (occupancy 8%, hbm 27%); k_wa+k_offc merged.
// ============================================================================

typedef short short8 __attribute__((ext_vector_type(8)));
typedef float f32x4 __attribute__((ext_vector_type(4)));

constexpr int Bn = 16, Cn = 64, Hn = 128, Wn = 128, NP = 32;
constexpr float EPSV = 1e-5f;
constexpr int PX = 612;        // pixels per tile: 18 rows x 34 cols
constexpr int SLOTS = 1224;    // PX * 2 channel-halves

__device__ __forceinline__ unsigned short bf16r(float f) {
  unsigned u = __builtin_bit_cast(unsigned, f);
  u += 0x7fffu + ((u >> 16) & 1u);
  return (unsigned short)(u >> 16);
}
__device__ __forceinline__ int swz(int p, int hh) {
  return (p * 32 + hh * 16) ^ (((p >> 2) & 7) << 4);
}

// ---- fused precompute: blocks 0..15 -> weight table WA, block 16 -> offC ----
// WA: short8 idx = s*1024 + chunk*256 + (mt*64 + g*16 + r)
//     elem j: o = mt*16+r, tap t36 = 2s + (g>>1), i = chunk*16 + (g&1)*8 + j
//     value = W6[o][i][t36]*s0[i]*(1-a) + a*delta_{o,i}*[tap interior]
__global__ void k_pre(const float* __restrict__ wv, const float* __restrict__ g0,
                      const float* __restrict__ b0, const float* __restrict__ m0,
                      const float* __restrict__ v0, const float* __restrict__ bv,
                      const float* __restrict__ alpha,
                      unsigned short* __restrict__ WA, float* __restrict__ offC) {
  const float al = alpha[0];
  const float oma = 1.0f - al;
  if (blockIdx.x < 16) {
    int t = blockIdx.x * 256 + threadIdx.x;   // t < 4096
    int o = t >> 6, i = t & 63;
    float s0 = g0[i] * rsqrtf(v0[i] + EPSV);
    float wl[3][3];
#pragma unroll
    for (int ky = 0; ky < 3; ++ky)
#pragma unroll
      for (int kx = 0; kx < 3; ++kx)
        wl[ky][kx] = wv[((o * Cn + i) * 3 + ky) * 3 + kx];
#pragma unroll
    for (int a = 0; a < 6; ++a) {
      int klo = (a - 3 < 0) ? 0 : a - 3, khi = (a < 2) ? a : 2;
#pragma unroll
      for (int b = 0; b < 6; ++b) {
        int llo = (b - 3 < 0) ? 0 : b - 3, lhi = (b < 2) ? b : 2;
        float s = 0.f;
        for (int ky = klo; ky <= khi; ++ky)
          for (int kx = llo; kx <= lhi; ++kx) s += wl[ky][kx];
        float val = s * s0 * oma;
        if (o == i && a >= 1 && a <= 4 && b >= 1 && b <= 4) val += al;
        int t36 = a * 6 + b;
        int g = (t36 & 1) * 2 + ((i >> 3) & 1);
        int idx8 = (t36 >> 1) * 1024 + (i >> 4) * 256 + ((o >> 4) * 64 + g * 16 + (o & 15));
        WA[idx8 * 8 + (i & 7)] = bf16r(val);
      }
    }
  } else {
    // border-class offsets: offC[cls][o], cls = ic*3+jc
    int o = threadIdx.x & 63;
    const int N0[3] = {3, 4, 4}, N1[3] = {4, 4, 4}, N2[3] = {4, 4, 3};
    for (int cls = threadIdx.x >> 6; cls < 9; cls += 4) {
      int ic = cls / 3, jc = cls % 3;
      const int* Na = (ic == 0) ? N0 : ((ic == 1) ? N1 : N2);
      const int* Nb = (jc == 0) ? N0 : ((jc == 1) ? N1 : N2);
      float acc = 0.f;
      for (int i = 0; i < Cn; ++i) {
        float s0 = g0[i] * rsqrtf(v0[i] + EPSV);
        float o0 = b0[i] - m0[i] * s0;
        float s = 0.f;
#pragma unroll
        for (int ky = 0; ky < 3; ++ky) {
          float rs = 0.f;
#pragma unroll
          for (int kx = 0; kx < 3; ++kx)
            rs += wv[((o * Cn + i) * 3 + ky) * 3 + kx] * (float)Nb[kx];
          s += rs * (float)Na[ky];
        }
        acc += o0 * s;
      }
      offC[cls * 64 + o] = oma * (acc + 16.f * bv[o]);
    }
  }
}

// ---- fused MFMA conv (+ diag alpha term) + offset epilogue ----
// Block: batch b, 4x8 patch tile (16x32 px + halo -> 18x34), 64 out-ch.
// grid 512 = 2 blocks/CU, 8 waves/CU.
__global__ __launch_bounds__(256, 2) void k_conv(const float* __restrict__ x,
    const unsigned short* __restrict__ WA, const float* __restrict__ offC,
    float* __restrict__ out) {
  __shared__ alignas(128) unsigned short xs[2][PX * 16];  // 2 x 19584 B

  const int tid = threadIdx.x;
  const int b = blockIdx.z, by = blockIdx.y, bx = blockIdx.x;
  const int lane = tid & 63, w = tid >> 6;
  const int r = lane & 15, g = lane >> 4;       // g in 0..3
  const int g1 = g >> 1, hh16 = (g & 1) * 16;
  const float* xb = x + (size_t)b * (Cn * Hn * Wn);
  const int grow0 = by * 16 - 1, gcol0 = bx * 32 - 1;

  // staging slot precompute: slot s = hh*PX + pixel, pixel = rr*34+cc
  int sg[5], sl[5], sv[5];
#pragma unroll
  for (int j = 0; j < 5; ++j) {
    int s = tid + j * 256;
    int valid = (s < SLOTS);
    int hh = (s >= PX) ? 1 : 0;
    int pixel = valid ? (s - hh * PX) : 0;
    int rr = pixel / 34;
    int cc = pixel - rr * 34;
    int gr = grow0 + rr, gc = gcol0 + cc;
    int inb = valid && ((unsigned)gr < 128u) && ((unsigned)gc < 128u);
    sg[j] = hh * (8 * 16384) + gr * 128 + gc;
    sl[j] = swz(pixel, hh);
    sv[j] = valid ? (inb ? 2 : 1) : 0;
  }

  // B-frag base: patch P = nt*16 + r -> pi = nt*2 + (r>>3), pj = r&7
  const int pbase = (r >> 3) * 136 + (r & 7) * 4 + g1;

  f32x4 acc[4];  // [parity*2 + nt]
#pragma unroll
  for (int t = 0; t < 4; ++t)
#pragma unroll
    for (int i = 0; i < 4; ++i) acc[t][i] = 0.f;
  float st[5][8];

  auto LOAD = [&](int ch) {
    const float* xc = xb + (size_t)(ch * 16) * 16384;
#pragma unroll
    for (int j = 0; j < 5; ++j)
#pragma unroll
      for (int k = 0; k < 8; ++k)
        st[j][k] = (sv[j] == 2) ? xc[sg[j] + k * 16384] : 0.f;
  };
  auto WRITE = [&](int ch) {
    char* base = (char*)&xs[ch & 1][0];
#pragma unroll
    for (int j = 0; j < 5; ++j) {
      if (sv[j]) {
        short8 w8;
#pragma unroll
        for (int k = 0; k < 8; ++k) w8[k] = (short)bf16r(st[j][k]);
        *(short8*)(base + sl[j]) = w8;
      }
    }
  };
  auto COMPUTE = [&](int ch) {
    const char* base = (const char*)&xs[ch & 1][0];
    const short8* wv8 = (const short8*)WA;
    const int lc = ch * 256 + tid;  // = ch*256 + w*64 + g*16 + r
    short8 af[18];
#pragma unroll
    for (int s = 0; s < 18; ++s) af[s] = wv8[s * 1024 + lc];
#pragma unroll
    for (int s = 0; s < 18; ++s) {
      const int toff = ((2 * s) / 6) * 34 + (2 * s) % 6;  // compile-time
      int p = pbase + toff;
      int a0 = (p * 32) ^ (((p >> 2) & 7) << 4) ^ hh16;
      int a1 = (a0 + 8704) ^ 64;          // swz(p+272) identity
      short8 bv0 = *(const short8*)(base + a0);
      short8 bv1 = *(const short8*)(base + a1);
      const int q = (s & 1) * 2;
      acc[q + 0] = __builtin_amdgcn_mfma_f32_16x16x32_bf16(af[s], bv0, acc[q + 0], 0, 0, 0);
      acc[q + 1] = __builtin_amdgcn_mfma_f32_16x16x32_bf16(af[s], bv1, acc[q + 1], 0, 0, 0);
    }
  };

  LOAD(0);
  WRITE(0);
  __syncthreads();
#pragma unroll
  for (int c = 0; c < 4; ++c) {
    if (c < 3) LOAD(c + 1);   // issue next-chunk global loads early (T14)
    COMPUTE(c);               // mfma while loads are in flight
    if (c < 3) {
      WRITE(c + 1);           // vmcnt + cvt + ds_write (other buffer)
      __syncthreads();
    }
  }

  // epilogue: D col = lane&15 = r -> patch P = nt*16+r; row = g*4+reg -> o
#pragma unroll
  for (int nt = 0; nt < 2; ++nt) {
    const int P = nt * 16 + r;
    const int pig = by * 4 + (P >> 3), pjg = bx * 8 + (P & 7);
    const int icl = (pig == 0) ? 0 : ((pig == 31) ? 2 : 1);
    const int jcl = (pjg == 0) ? 0 : ((pjg == 31) ? 2 : 1);
    const float* offr = offC + (icl * 3 + jcl) * 64;
    float* ob = out + (((size_t)b * 64) * NP + pig) * NP + pjg;
#pragma unroll
    for (int reg = 0; reg < 4; ++reg) {
      const int o = w * 16 + g * 4 + reg;
      float v = acc[nt][reg] + acc[2 + nt][reg];
      ob[(size_t)o * 1024] = v + offr[o];
    }
  }
}

extern "C" void kernel_launch(void* const* d_in, const int* in_sizes, int n_in,
                              void* d_out, int out_size, void* d_ws, size_t ws_size,
                              hipStream_t stream) {
  const float* x     = (const float*)d_in[0];
  const float* g0    = (const float*)d_in[1];
  const float* b0    = (const float*)d_in[2];
  const float* m0    = (const float*)d_in[3];
  const float* v0    = (const float*)d_in[4];
  const float* wv    = (const float*)d_in[15];
  const float* bv    = (const float*)d_in[16];
  const float* alpha = (const float*)d_in[17];
  float* out = (float*)d_out;

  unsigned short* WA = (unsigned short*)d_ws;          // 18*1024 short8 = 288 KB
  float* offC = (float*)(WA + 18 * 1024 * 8);          // 9*64 floats

  k_pre<<<17, 256, 0, stream>>>(wv, g0, b0, m0, v0, bv, alpha, WA, offC);
  dim3 grid(NP / 8, NP / 4, Bn);
  k_conv<<<grid, 256, 0, stream>>>(x, WA, offC, out);
}

// Round 7
// 53.099 us; speedup vs baseline: 1.9448x; 1.9448x over previous
//
#include <hip/hip_runtime.h>

// ============================================================================
// AttenPool: softmax-over-L summed over L == 1, so
//   out[b,c,P] = (1-a)*( sumpool4(conv3(BN(x),wv))[c,P] + 16*bv[c] )
//                + a*sumpool4(x)[c,P]
// sumpool4 o conv3 == 6x6 stride-4 conv (W6); BN scale folds into W6; BN offset
// -> per-(outch, border-class) constant (9 classes). The per-channel a*x
// patch-sum is ALSO a 6x6 stride-4 conv (weight a*delta_{o,i}, interior taps)
// -> folded into the same weight table.
// Conv = implicit GEMM on mfma_f32_16x16x32_bf16; A and B fragments use the
// IDENTICAL (lane-group, elem)->(tap, channel) map so any internal HW
// k-permutation cancels. LDS x tile [pixel][16ch] bf16, double-buffered,
// bijective swizzle addr = (p*32+hh*16) ^ (((p>>2)&7)<<4).
// Round 7: (1) k_pre offC straggler (55us: 3 serial cls x 64 i dependent-load
// chain in ONE block) -> i-reduction parallelized across 256 threads + LDS
// reduce. (2) k_conv vmcnt ordering: A-frag loads now issued BEFORE next
// chunk's x loads, so the MFMA phase waits vmcnt(40) (af only) instead of
// draining all 40 HBM staging loads each chunk.
// ============================================================================

typedef short short8 __attribute__((ext_vector_type(8)));
typedef float f32x4 __attribute__((ext_vector_type(4)));

constexpr int Bn = 16, Cn = 64, Hn = 128, Wn = 128, NP = 32;
constexpr float EPSV = 1e-5f;
constexpr int PX = 612;        // pixels per tile: 18 rows x 34 cols
constexpr int SLOTS = 1224;    // PX * 2 channel-halves

__device__ __forceinline__ unsigned short bf16r(float f) {
  unsigned u = __builtin_bit_cast(unsigned, f);
  u += 0x7fffu + ((u >> 16) & 1u);
  return (unsigned short)(u >> 16);
}
__device__ __forceinline__ int swz(int p, int hh) {
  return (p * 32 + hh * 16) ^ (((p >> 2) & 7) << 4);
}

// ---- fused precompute: blocks 0..15 -> weight table WA, block 16 -> offC ----
// WA: short8 idx = s*1024 + chunk*256 + (mt*64 + g*16 + r)
//     elem j: o = mt*16+r, tap t36 = 2s + (g>>1), i = chunk*16 + (g&1)*8 + j
//     value = W6[o][i][t36]*s0[i]*(1-a) + a*delta_{o,i}*[tap interior]
__global__ void k_pre(const float* __restrict__ wv, const float* __restrict__ g0,
                      const float* __restrict__ b0, const float* __restrict__ m0,
                      const float* __restrict__ v0, const float* __restrict__ bv,
                      const float* __restrict__ alpha,
                      unsigned short* __restrict__ WA, float* __restrict__ offC) {
  __shared__ float red[4][64][9];
  const float al = alpha[0];
  const float oma = 1.0f - al;
  if (blockIdx.x < 16) {
    int t = blockIdx.x * 256 + threadIdx.x;   // t < 4096
    int o = t >> 6, i = t & 63;
    float s0 = g0[i] * rsqrtf(v0[i] + EPSV);
    float wl[3][3];
#pragma unroll
    for (int ky = 0; ky < 3; ++ky)
#pragma unroll
      for (int kx = 0; kx < 3; ++kx)
        wl[ky][kx] = wv[((o * Cn + i) * 3 + ky) * 3 + kx];
#pragma unroll
    for (int a = 0; a < 6; ++a) {
      int klo = (a - 3 < 0) ? 0 : a - 3, khi = (a < 2) ? a : 2;
#pragma unroll
      for (int b = 0; b < 6; ++b) {
        int llo = (b - 3 < 0) ? 0 : b - 3, lhi = (b < 2) ? b : 2;
        float s = 0.f;
        for (int ky = klo; ky <= khi; ++ky)
          for (int kx = llo; kx <= lhi; ++kx) s += wl[ky][kx];
        float val = s * s0 * oma;
        if (o == i && a >= 1 && a <= 4 && b >= 1 && b <= 4) val += al;
        int t36 = a * 6 + b;
        int g = (t36 & 1) * 2 + ((i >> 3) & 1);
        int idx8 = (t36 >> 1) * 1024 + (i >> 4) * 256 + ((o >> 4) * 64 + g * 16 + (o & 15));
        WA[idx8 * 8 + (i & 7)] = bf16r(val);
      }
    }
  } else {
    // offC[cls][o]: phase 1 = per-(o, i-group) tap partials, wide over i
    const int o = threadIdx.x & 63, q = threadIdx.x >> 6;
    float P[9] = {0.f, 0.f, 0.f, 0.f, 0.f, 0.f, 0.f, 0.f, 0.f};
#pragma unroll 4
    for (int ii = 0; ii < 16; ++ii) {
      int i = q * 16 + ii;
      float s0 = g0[i] * rsqrtf(v0[i] + EPSV);
      float o0 = b0[i] - m0[i] * s0;
      const float* wp = wv + ((size_t)o * 64 + i) * 9;
#pragma unroll
      for (int kk = 0; kk < 9; ++kk) P[kk] += o0 * wp[kk];
    }
#pragma unroll
    for (int kk = 0; kk < 9; ++kk) red[q][o][kk] = P[kk];
    __syncthreads();
    // phase 2: combine with border-class tap counts
    const float NT[3][3] = {{3.f, 4.f, 4.f}, {4.f, 4.f, 4.f}, {4.f, 4.f, 3.f}};
    for (int idx = threadIdx.x; idx < 576; idx += 256) {
      int cls = idx >> 6, o2 = idx & 63;
      int ic = cls / 3, jc = cls % 3;
      float s = 0.f;
#pragma unroll
      for (int ky = 0; ky < 3; ++ky)
#pragma unroll
        for (int kx = 0; kx < 3; ++kx) {
          int kk = ky * 3 + kx;
          float Pv = (red[0][o2][kk] + red[1][o2][kk]) + (red[2][o2][kk] + red[3][o2][kk]);
          s += Pv * NT[ic][ky] * NT[jc][kx];
        }
      offC[cls * 64 + o2] = oma * (s + 16.f * bv[o2]);
    }
  }
}

// ---- fused MFMA conv (+ diag alpha term) + offset epilogue ----
// Block: batch b, 4x8 patch tile (16x32 px + halo -> 18x34), 64 out-ch.
// grid 512 = 2 blocks/CU, 8 waves/CU.
__global__ __launch_bounds__(256, 2) void k_conv(const float* __restrict__ x,
    const unsigned short* __restrict__ WA, const float* __restrict__ offC,
    float* __restrict__ out) {
  __shared__ alignas(128) unsigned short xs[2][PX * 16];  // 2 x 19584 B

  const int tid = threadIdx.x;
  const int b = blockIdx.z, by = blockIdx.y, bx = blockIdx.x;
  const int lane = tid & 63, w = tid >> 6;
  const int r = lane & 15, g = lane >> 4;       // g in 0..3
  const int g1 = g >> 1, hh16 = (g & 1) * 16;
  const float* xb = x + (size_t)b * (Cn * Hn * Wn);
  const int grow0 = by * 16 - 1, gcol0 = bx * 32 - 1;

  // staging slot precompute: slot s = hh*PX + pixel, pixel = rr*34+cc
  int sg[5], sl[5], sv[5];
#pragma unroll
  for (int j = 0; j < 5; ++j) {
    int s = tid + j * 256;
    int valid = (s < SLOTS);
    int hh = (s >= PX) ? 1 : 0;
    int pixel = valid ? (s - hh * PX) : 0;
    int rr = pixel / 34;
    int cc = pixel - rr * 34;
    int gr = grow0 + rr, gc = gcol0 + cc;
    int inb = valid && ((unsigned)gr < 128u) && ((unsigned)gc < 128u);
    sg[j] = hh * (8 * 16384) + gr * 128 + gc;
    sl[j] = swz(pixel, hh);
    sv[j] = valid ? (inb ? 2 : 1) : 0;
  }

  // B-frag base: patch P = nt*16 + r -> pi = nt*2 + (r>>3), pj = r&7
  const int pbase = (r >> 3) * 136 + (r & 7) * 4 + g1;

  f32x4 acc[4];  // [parity*2 + nt]
#pragma unroll
  for (int t = 0; t < 4; ++t)
#pragma unroll
    for (int i = 0; i < 4; ++i) acc[t][i] = 0.f;
  float st[5][8];
  short8 af[18];

  auto AFLOAD = [&](int ch) {
    const short8* wv8 = (const short8*)WA;
    const int lc = ch * 256 + tid;  // = ch*256 + w*64 + g*16 + r
#pragma unroll
    for (int s = 0; s < 18; ++s) af[s] = wv8[s * 1024 + lc];
  };
  auto LOAD = [&](int ch) {
    const float* xc = xb + (size_t)(ch * 16) * 16384;
#pragma unroll
    for (int j = 0; j < 5; ++j)
#pragma unroll
      for (int k = 0; k < 8; ++k)
        st[j][k] = (sv[j] == 2) ? xc[sg[j] + k * 16384] : 0.f;
  };
  auto WRITE = [&](int ch) {
    char* base = (char*)&xs[ch & 1][0];
#pragma unroll
    for (int j = 0; j < 5; ++j) {
      if (sv[j]) {
        short8 w8;
#pragma unroll
        for (int k = 0; k < 8; ++k) w8[k] = (short)bf16r(st[j][k]);
        *(short8*)(base + sl[j]) = w8;
      }
    }
  };
  auto MFMA = [&](int ch) {
    const char* base = (const char*)&xs[ch & 1][0];
#pragma unroll
    for (int s = 0; s < 18; ++s) {
      const int toff = ((2 * s) / 6) * 34 + (2 * s) % 6;  // compile-time
      int p = pbase + toff;
      int a0 = (p * 32) ^ (((p >> 2) & 7) << 4) ^ hh16;
      int a1 = (a0 + 8704) ^ 64;          // swz(p+272) identity
      short8 bv0 = *(const short8*)(base + a0);
      short8 bv1 = *(const short8*)(base + a1);
      const int q = (s & 1) * 2;
      acc[q + 0] = __builtin_amdgcn_mfma_f32_16x16x32_bf16(af[s], bv0, acc[q + 0], 0, 0, 0);
      acc[q + 1] = __builtin_amdgcn_mfma_f32_16x16x32_bf16(af[s], bv1, acc[q + 1], 0, 0, 0);
    }
  };

  LOAD(0);
  WRITE(0);
  __syncthreads();
#pragma unroll
  for (int c = 0; c < 4; ++c) {
    AFLOAD(c);                              // 18 L2 loads issued FIRST
    __builtin_amdgcn_sched_barrier(0);      // pin: af before next-chunk x loads
    if (c < 3) LOAD(c + 1);                 // 40 HBM loads (stay in flight)
    MFMA(c);                                // waits vmcnt(40) -> af only
    if (c < 3) {
      WRITE(c + 1);                         // vmcnt(0) + cvt + ds_write
      __syncthreads();
    }
  }

  // epilogue: D col = lane&15 = r -> patch P = nt*16+r; row = g*4+reg -> o
#pragma unroll
  for (int nt = 0; nt < 2; ++nt) {
    const int P = nt * 16 + r;
    const int pig = by * 4 + (P >> 3), pjg = bx * 8 + (P & 7);
    const int icl = (pig == 0) ? 0 : ((pig == 31) ? 2 : 1);
    const int jcl = (pjg == 0) ? 0 : ((pjg == 31) ? 2 : 1);
    const float* offr = offC + (icl * 3 + jcl) * 64;
    float* ob = out + (((size_t)b * 64) * NP + pig) * NP + pjg;
#pragma unroll
    for (int reg = 0; reg < 4; ++reg) {
      const int o = w * 16 + g * 4 + reg;
      float v = acc[nt][reg] + acc[2 + nt][reg];
      ob[(size_t)o * 1024] = v + offr[o];
    }
  }
}

extern "C" void kernel_launch(void* const* d_in, const int* in_sizes, int n_in,
                              void* d_out, int out_size, void* d_ws, size_t ws_size,
                              hipStream_t stream) {
  const float* x     = (const float*)d_in[0];
  const float* g0    = (const float*)d_in[1];
  const float* b0    = (const float*)d_in[2];
  const float* m0    = (const float*)d_in[3];
  const float* v0    = (const float*)d_in[4];
  const float* wv    = (const float*)d_in[15];
  const float* bv    = (const float*)d_in[16];
  const float* alpha = (const float*)d_in[17];
  float* out = (float*)d_out;

  unsigned short* WA = (unsigned short*)d_ws;          // 18*1024 short8 = 288 KB
  float* offC = (float*)(WA + 18 * 1024 * 8);          // 9*64 floats

  k_pre<<<17, 256, 0, stream>>>(wv, g0, b0, m0, v0, bv, alpha, WA, offC);
  dim3 grid(NP / 8, NP / 4, Bn);
  k_conv<<<grid, 256, 0, stream>>>(x, WA, offC, out);
}

// Round 9
// 44.076 us; speedup vs baseline: 2.3429x; 1.2047x over previous
//
#include <hip/hip_runtime.h>

// ============================================================================
// AttenPool: softmax-over-L summed over L == 1, so
//   out[b,c,P] = (1-a)*( sumpool4(conv3(BN(x),wv))[c,P] + 16*bv[c] )
//                + a*sumpool4(x)[c,P]
// == 6x6 stride-4 conv (W6) with BN scale folded in, per-channel alpha term on
// the weight diagonal, BN offset as per-(o, border-class) constant.
// Implicit GEMM on mfma_f32_16x16x32_bf16 (A/B share one (lane,elem)->(tap,ch)
// map so HW k-permutation cancels). LDS x tile [pixel][16ch] bf16, dbuf,
// bijective swizzle addr = (p*32+hh*16) ^ (((p>>2)&7)<<4).
// Round 9: r8's failure was WRITE indexing xs[buf] instead of xs[buf & 1]
// (chunks 2,3 wrote past the double-buffer -> channels 32..63 MFMA'd against
// stale data; absmax 17.7 ~ half the conv magnitude). One-token fix.
// Two-pass structure unchanged:
//   k_cvt: x (NCHW fp32) -> x_t[b][cg4][px][ch16] bf16 once (pure stream).
//   k_conv: staging = 5 coalesced short8 loads (source pre-swizzled with the
//   inverse swizzle -> LDS image identical to r7) + 5 linear ds_write_b128.
//   AF loads issue before staging loads (vmcnt FIFO).
// ============================================================================

typedef short short8 __attribute__((ext_vector_type(8)));
typedef float f32x4 __attribute__((ext_vector_type(4)));

constexpr int Bn = 16, Cn = 64, Hn = 128, Wn = 128, NP = 32;
constexpr float EPSV = 1e-5f;
constexpr int PX = 612;        // pixels per tile: 18 rows x 34 cols
constexpr int SLOTS = 1224;    // PX * 2 channel-halves

__device__ __forceinline__ unsigned short bf16r(float f) {
  unsigned u = __builtin_bit_cast(unsigned, f);
  u += 0x7fffu + ((u >> 16) & 1u);
  return (unsigned short)(u >> 16);
}

// ---- fused precompute: blocks 0..15 -> weight table WA, block 16 -> offC ----
__global__ void k_pre(const float* __restrict__ wv, const float* __restrict__ g0,
                      const float* __restrict__ b0, const float* __restrict__ m0,
                      const float* __restrict__ v0, const float* __restrict__ bv,
                      const float* __restrict__ alpha,
                      unsigned short* __restrict__ WA, float* __restrict__ offC) {
  __shared__ float red[4][64][9];
  const float al = alpha[0];
  const float oma = 1.0f - al;
  if (blockIdx.x < 16) {
    int t = blockIdx.x * 256 + threadIdx.x;   // t < 4096
    int o = t >> 6, i = t & 63;
    float s0 = g0[i] * rsqrtf(v0[i] + EPSV);
    float wl[3][3];
#pragma unroll
    for (int ky = 0; ky < 3; ++ky)
#pragma unroll
      for (int kx = 0; kx < 3; ++kx)
        wl[ky][kx] = wv[((o * Cn + i) * 3 + ky) * 3 + kx];
#pragma unroll
    for (int a = 0; a < 6; ++a) {
      int klo = (a - 3 < 0) ? 0 : a - 3, khi = (a < 2) ? a : 2;
#pragma unroll
      for (int b = 0; b < 6; ++b) {
        int llo = (b - 3 < 0) ? 0 : b - 3, lhi = (b < 2) ? b : 2;
        float s = 0.f;
        for (int ky = klo; ky <= khi; ++ky)
          for (int kx = llo; kx <= lhi; ++kx) s += wl[ky][kx];
        float val = s * s0 * oma;
        if (o == i && a >= 1 && a <= 4 && b >= 1 && b <= 4) val += al;
        int t36 = a * 6 + b;
        int g = (t36 & 1) * 2 + ((i >> 3) & 1);
        int idx8 = (t36 >> 1) * 1024 + (i >> 4) * 256 + ((o >> 4) * 64 + g * 16 + (o & 15));
        WA[idx8 * 8 + (i & 7)] = bf16r(val);
      }
    }
  } else {
    // offC[cls][o]: phase 1 = per-(o, i-group) tap partials, wide over i
    const int o = threadIdx.x & 63, q = threadIdx.x >> 6;
    float P[9] = {0.f, 0.f, 0.f, 0.f, 0.f, 0.f, 0.f, 0.f, 0.f};
#pragma unroll 4
    for (int ii = 0; ii < 16; ++ii) {
      int i = q * 16 + ii;
      float s0 = g0[i] * rsqrtf(v0[i] + EPSV);
      float o0 = b0[i] - m0[i] * s0;
      const float* wp = wv + ((size_t)o * 64 + i) * 9;
#pragma unroll
      for (int kk = 0; kk < 9; ++kk) P[kk] += o0 * wp[kk];
    }
#pragma unroll
    for (int kk = 0; kk < 9; ++kk) red[q][o][kk] = P[kk];
    __syncthreads();
    const float NT[3][3] = {{3.f, 4.f, 4.f}, {4.f, 4.f, 4.f}, {4.f, 4.f, 3.f}};
    for (int idx = threadIdx.x; idx < 576; idx += 256) {
      int cls = idx >> 6, o2 = idx & 63;
      int ic = cls / 3, jc = cls % 3;
      float s = 0.f;
#pragma unroll
      for (int ky = 0; ky < 3; ++ky)
#pragma unroll
        for (int kx = 0; kx < 3; ++kx) {
          int kk = ky * 3 + kx;
          float Pv = (red[0][o2][kk] + red[1][o2][kk]) + (red[2][o2][kk] + red[3][o2][kk]);
          s += Pv * NT[ic][ky] * NT[jc][kx];
        }
      offC[cls * 64 + o2] = oma * (s + 16.f * bv[o2]);
    }
  }
}

// ---- x (NCHW fp32) -> x_t[b][cg][px][ch16] bf16, LDS transpose ----
__global__ __launch_bounds__(256) void k_cvt(const float* __restrict__ x,
                                             unsigned short* __restrict__ xt) {
  __shared__ alignas(16) unsigned short ts[4096];  // 256 px x 16 ch, swizzled
  const int tid = threadIdx.x;
  const int pxb = blockIdx.x, cg = blockIdx.y, b = blockIdx.z;
  const int qd = tid & 63;
  const float* src = x + ((size_t)(b * 64 + cg * 16)) * 16384 + pxb * 256 + qd * 4;
  char* lb = (char*)ts;
#pragma unroll
  for (int j = 0; j < 4; ++j) {
    int k = (tid >> 6) + j * 4;
    float4 v = *(const float4*)(src + (size_t)k * 16384);
    int hh16 = (k >> 3) * 16, choff = (k & 7) * 2;
    float vv[4] = {v.x, v.y, v.z, v.w};
#pragma unroll
    for (int e = 0; e < 4; ++e) {
      int p = qd * 4 + e;
      int a = ((p * 32 + hh16) ^ (((p >> 2) & 7) << 4)) + choff;
      *(unsigned short*)(lb + a) = bf16r(vv[e]);
    }
  }
  __syncthreads();
  unsigned short* xo = xt + ((size_t)(b * 4 + cg) * 16384 + (size_t)pxb * 256) * 16;
#pragma unroll
  for (int j = 0; j < 2; ++j) {
    int s = tid + j * 256;
    int px = s >> 1, hh = s & 1;
    int a = (px * 32 + hh * 16) ^ (((px >> 2) & 7) << 4);
    short8 v = *(const short8*)(lb + a);
    *(short8*)(xo + (size_t)s * 8) = v;
  }
}

// ---- fused MFMA conv (+ diag alpha term) + offset epilogue ----
// Block: batch b, 4x8 patch tile (16x32 px + halo -> 18x34), 64 out-ch.
__global__ __launch_bounds__(256, 2) void k_conv(const unsigned short* __restrict__ xt,
    const unsigned short* __restrict__ WA, const float* __restrict__ offC,
    float* __restrict__ out) {
  __shared__ alignas(128) unsigned short xs[2][SLOTS * 8];  // 2 x 19584 B

  const int tid = threadIdx.x;
  const int b = blockIdx.z, by = blockIdx.y, bx = blockIdx.x;
  const int lane = tid & 63, w = tid >> 6;
  const int r = lane & 15, g = lane >> 4;       // g in 0..3
  const int g1 = g >> 1, hh16 = (g & 1) * 16;
  const char* xtb = (const char*)xt + (size_t)b * 2097152;  // b-plane (4 cg)
  const int grow0 = by * 16 - 1, gcol0 = bx * 32 - 1;

  // source offsets: dest slot s (linear) -> inverse-swizzle -> (p,hh) -> x_t
  int srcoff[5];
#pragma unroll
  for (int j = 0; j < 5; ++j) {
    int s = tid + j * 256;
    int L = s << 4;
    int f = (L >> 7) & 7;
    int orig = L ^ (f << 4);
    int p = orig >> 5, hh = (orig >> 4) & 1;
    int rr = p / 34, cc = p - rr * 34;
    int gr = grow0 + rr, gc = gcol0 + cc;
    bool inb = ((unsigned)gr < 128u) && ((unsigned)gc < 128u);
    srcoff[j] = inb ? ((gr * 128 + gc) * 32 + hh * 16) : -1;
  }

  // B-frag base: patch P = nt*16 + r -> pi = nt*2 + (r>>3), pj = r&7
  const int pbase = (r >> 3) * 136 + (r & 7) * 4 + g1;

  f32x4 acc[4];  // [parity*2 + nt]
#pragma unroll
  for (int t = 0; t < 4; ++t)
#pragma unroll
    for (int i = 0; i < 4; ++i) acc[t][i] = 0.f;
  short8 st[5];
  short8 af[18];

  auto AFLOAD = [&](int ch) {
    const short8* wv8 = (const short8*)WA;
    const int lc = ch * 256 + tid;
#pragma unroll
    for (int s = 0; s < 18; ++s) af[s] = wv8[s * 1024 + lc];
  };
  auto LOAD = [&](int cg) {
    const char* base = xtb + (size_t)cg * 524288;
#pragma unroll
    for (int j = 0; j < 5; ++j) {
      if (j < 4 || tid < SLOTS - 1024) {
        st[j] = (srcoff[j] >= 0) ? *(const short8*)(base + srcoff[j])
                                 : (short8)(short)0;
      }
    }
  };
  auto WRITE = [&](int buf) {
    char* lb = (char*)&xs[buf & 1][0];
#pragma unroll
    for (int j = 0; j < 5; ++j)
      if (j < 4 || tid < SLOTS - 1024)
        *(short8*)(lb + (tid + j * 256) * 16) = st[j];
  };
  auto MFMA = [&](int ch) {
    const char* base = (const char*)&xs[ch & 1][0];
#pragma unroll
    for (int s = 0; s < 18; ++s) {
      const int toff = ((2 * s) / 6) * 34 + (2 * s) % 6;  // compile-time
      int p = pbase + toff;
      int a0 = (p * 32) ^ (((p >> 2) & 7) << 4) ^ hh16;
      int a1 = (a0 + 8704) ^ 64;          // swz(p+272) identity
      short8 bv0 = *(const short8*)(base + a0);
      short8 bv1 = *(const short8*)(base + a1);
      const int q = (s & 1) * 2;
      acc[q + 0] = __builtin_amdgcn_mfma_f32_16x16x32_bf16(af[s], bv0, acc[q + 0], 0, 0, 0);
      acc[q + 1] = __builtin_amdgcn_mfma_f32_16x16x32_bf16(af[s], bv1, acc[q + 1], 0, 0, 0);
    }
  };

  LOAD(0);
  WRITE(0);
  __syncthreads();
#pragma unroll
  for (int c = 0; c < 4; ++c) {
    AFLOAD(c);                              // 18 L2 loads first (oldest in FIFO
    __builtin_amdgcn_sched_barrier(0);      //  -> af waits never drain staging)
    if (c < 3) LOAD(c + 1);                 // 5 coalesced short8 loads
    __builtin_amdgcn_sched_barrier(0);
    MFMA(c);
    if (c < 3) {
      WRITE(c + 1);                         // 5 linear ds_write_b128
      __syncthreads();
    }
  }

  // epilogue: D col = lane&15 = r -> patch P = nt*16+r; row = g*4+reg -> o
#pragma unroll
  for (int nt = 0; nt < 2; ++nt) {
    const int P = nt * 16 + r;
    const int pig = by * 4 + (P >> 3), pjg = bx * 8 + (P & 7);
    const int icl = (pig == 0) ? 0 : ((pig == 31) ? 2 : 1);
    const int jcl = (pjg == 0) ? 0 : ((pjg == 31) ? 2 : 1);
    const float* offr = offC + (icl * 3 + jcl) * 64;
    float* ob = out + (((size_t)b * 64) * NP + pig) * NP + pjg;
#pragma unroll
    for (int reg = 0; reg < 4; ++reg) {
      const int o = w * 16 + g * 4 + reg;
      float v = acc[nt][reg] + acc[2 + nt][reg];
      ob[(size_t)o * 1024] = v + offr[o];
    }
  }
}

extern "C" void kernel_launch(void* const* d_in, const int* in_sizes, int n_in,
                              void* d_out, int out_size, void* d_ws, size_t ws_size,
                              hipStream_t stream) {
  const float* x     = (const float*)d_in[0];
  const float* g0    = (const float*)d_in[1];
  const float* b0    = (const float*)d_in[2];
  const float* m0    = (const float*)d_in[3];
  const float* v0    = (const float*)d_in[4];
  const float* wv    = (const float*)d_in[15];
  const float* bv    = (const float*)d_in[16];
  const float* alpha = (const float*)d_in[17];
  float* out = (float*)d_out;

  unsigned short* WA = (unsigned short*)d_ws;              // 288 KB at offset 0
  float* offC = (float*)((char*)d_ws + 294912);            // 9*64 floats
  unsigned short* xt = (unsigned short*)((char*)d_ws + 524288);  // 32 MiB

  k_pre<<<17, 256, 0, stream>>>(wv, g0, b0, m0, v0, bv, alpha, WA, offC);
  k_cvt<<<dim3(64, 4, 16), 256, 0, stream>>>(x, xt);
  dim3 grid(NP / 8, NP / 4, Bn);
  k_conv<<<grid, 256, 0, stream>>>(xt, WA, offC, out);
}

// Round 10
// 38.689 us; speedup vs baseline: 2.6691x; 1.1392x over previous
//
#include <hip/hip_runtime.h>

// ============================================================================
// AttenPool: softmax-over-L summed over L == 1, so
//   out[b,c,P] = (1-a)*( sumpool4(conv3(BN(x),wv))[c,P] + 16*bv[c] )
//                + a*sumpool4(x)[c,P]
// == 6x6 stride-4 conv (W6) with BN scale folded in, per-channel alpha term on
// the weight diagonal, BN offset as per-(o, border-class) constant.
// Implicit GEMM on mfma_f32_16x16x32_bf16 (A/B share one (lane,elem)->(tap,ch)
// map so HW k-permutation cancels). LDS x tile [pixel][16ch] bf16, dbuf,
// bijective swizzle addr = (p*32+hh*16) ^ (((p>>2)&7)<<4).
// Round 10: r9 confirmed the vmem-transaction model (staging instr 58->23 per
// chunk => k_conv 41 -> ~14us). This round is pure launch-structure: k_pre's
// 17 blocks merged into k_cvt's dispatch (k_pc, pre-blocks first so they hide
// under the cvt wave) -> saves k_pre's serial 3us + one inter-kernel gap.
// k_conv byte-identical to r9.
// ============================================================================

typedef short short8 __attribute__((ext_vector_type(8)));
typedef float f32x4 __attribute__((ext_vector_type(4)));

constexpr int Bn = 16, Cn = 64, Hn = 128, Wn = 128, NP = 32;
constexpr float EPSV = 1e-5f;
constexpr int PX = 612;        // pixels per tile: 18 rows x 34 cols
constexpr int SLOTS = 1224;    // PX * 2 channel-halves

__device__ __forceinline__ unsigned short bf16r(float f) {
  unsigned u = __builtin_bit_cast(unsigned, f);
  u += 0x7fffu + ((u >> 16) & 1u);
  return (unsigned short)(u >> 16);
}

// ---- merged precompute + transpose ----
// blocks 0..15: WA weight table; block 16: offC; blocks 17..4112: x -> x_t cvt.
__global__ __launch_bounds__(256) void k_pc(const float* __restrict__ x,
                      const float* __restrict__ wv, const float* __restrict__ g0,
                      const float* __restrict__ b0, const float* __restrict__ m0,
                      const float* __restrict__ v0, const float* __restrict__ bv,
                      const float* __restrict__ alpha,
                      unsigned short* __restrict__ WA, float* __restrict__ offC,
                      unsigned short* __restrict__ xt) {
  __shared__ alignas(16) char lds[9216];
  const int idx = blockIdx.x;
  const int tid = threadIdx.x;

  if (idx >= 17) {
    // ---- cvt: x (NCHW fp32) -> x_t[b][cg][px][ch16] bf16, LDS transpose ----
    unsigned short* ts = (unsigned short*)lds;   // 256 px x 16 ch, swizzled
    const int cidx = idx - 17;
    const int pxb = cidx & 63, cg = (cidx >> 6) & 3, b = cidx >> 8;
    const int qd = tid & 63;
    const float* src = x + ((size_t)(b * 64 + cg * 16)) * 16384 + pxb * 256 + qd * 4;
    char* lb = (char*)ts;
#pragma unroll
    for (int j = 0; j < 4; ++j) {
      int k = (tid >> 6) + j * 4;
      float4 v = *(const float4*)(src + (size_t)k * 16384);
      int hh16 = (k >> 3) * 16, choff = (k & 7) * 2;
      float vv[4] = {v.x, v.y, v.z, v.w};
#pragma unroll
      for (int e = 0; e < 4; ++e) {
        int p = qd * 4 + e;
        int a = ((p * 32 + hh16) ^ (((p >> 2) & 7) << 4)) + choff;
        *(unsigned short*)(lb + a) = bf16r(vv[e]);
      }
    }
    __syncthreads();
    unsigned short* xo = xt + ((size_t)(b * 4 + cg) * 16384 + (size_t)pxb * 256) * 16;
#pragma unroll
    for (int j = 0; j < 2; ++j) {
      int s = tid + j * 256;
      int px = s >> 1, hh = s & 1;
      int a = (px * 32 + hh * 16) ^ (((px >> 2) & 7) << 4);
      short8 v = *(const short8*)(lb + a);
      *(short8*)(xo + (size_t)s * 8) = v;
    }
    return;
  }

  const float al = alpha[0];
  const float oma = 1.0f - al;
  if (idx < 16) {
    // ---- WA: short8 idx = s*1024 + chunk*256 + (mt*64 + g*16 + r)
    //      elem j: o = mt*16+r, tap t36 = 2s+(g>>1), i = chunk*16+(g&1)*8+j
    //      value = W6[o][i][t36]*s0[i]*(1-a) + a*delta_{o,i}*[tap interior]
    int t = idx * 256 + tid;   // t < 4096
    int o = t >> 6, i = t & 63;
    float s0 = g0[i] * rsqrtf(v0[i] + EPSV);
    float wl[3][3];
#pragma unroll
    for (int ky = 0; ky < 3; ++ky)
#pragma unroll
      for (int kx = 0; kx < 3; ++kx)
        wl[ky][kx] = wv[((o * Cn + i) * 3 + ky) * 3 + kx];
#pragma unroll
    for (int a = 0; a < 6; ++a) {
      int klo = (a - 3 < 0) ? 0 : a - 3, khi = (a < 2) ? a : 2;
#pragma unroll
      for (int b = 0; b < 6; ++b) {
        int llo = (b - 3 < 0) ? 0 : b - 3, lhi = (b < 2) ? b : 2;
        float s = 0.f;
        for (int ky = klo; ky <= khi; ++ky)
          for (int kx = llo; kx <= lhi; ++kx) s += wl[ky][kx];
        float val = s * s0 * oma;
        if (o == i && a >= 1 && a <= 4 && b >= 1 && b <= 4) val += al;
        int t36 = a * 6 + b;
        int g = (t36 & 1) * 2 + ((i >> 3) & 1);
        int idx8 = (t36 >> 1) * 1024 + (i >> 4) * 256 + ((o >> 4) * 64 + g * 16 + (o & 15));
        WA[idx8 * 8 + (i & 7)] = bf16r(val);
      }
    }
  } else {
    // ---- offC[cls][o]: phase 1 = per-(o, i-group) tap partials ----
    float (*red)[64][9] = (float(*)[64][9])lds;
    const int o = tid & 63, q = tid >> 6;
    float P[9] = {0.f, 0.f, 0.f, 0.f, 0.f, 0.f, 0.f, 0.f, 0.f};
#pragma unroll 4
    for (int ii = 0; ii < 16; ++ii) {
      int i = q * 16 + ii;
      float s0 = g0[i] * rsqrtf(v0[i] + EPSV);
      float o0 = b0[i] - m0[i] * s0;
      const float* wp = wv + ((size_t)o * 64 + i) * 9;
#pragma unroll
      for (int kk = 0; kk < 9; ++kk) P[kk] += o0 * wp[kk];
    }
#pragma unroll
    for (int kk = 0; kk < 9; ++kk) red[q][o][kk] = P[kk];
    __syncthreads();
    const float NT[3][3] = {{3.f, 4.f, 4.f}, {4.f, 4.f, 4.f}, {4.f, 4.f, 3.f}};
    for (int i2 = tid; i2 < 576; i2 += 256) {
      int cls = i2 >> 6, o2 = i2 & 63;
      int ic = cls / 3, jc = cls % 3;
      float s = 0.f;
#pragma unroll
      for (int ky = 0; ky < 3; ++ky)
#pragma unroll
        for (int kx = 0; kx < 3; ++kx) {
          int kk = ky * 3 + kx;
          float Pv = (red[0][o2][kk] + red[1][o2][kk]) + (red[2][o2][kk] + red[3][o2][kk]);
          s += Pv * NT[ic][ky] * NT[jc][kx];
        }
      offC[cls * 64 + o2] = oma * (s + 16.f * bv[o2]);
    }
  }
}

// ---- fused MFMA conv (+ diag alpha term) + offset epilogue ----
// Block: batch b, 4x8 patch tile (16x32 px + halo -> 18x34), 64 out-ch.
__global__ __launch_bounds__(256, 2) void k_conv(const unsigned short* __restrict__ xt,
    const unsigned short* __restrict__ WA, const float* __restrict__ offC,
    float* __restrict__ out) {
  __shared__ alignas(128) unsigned short xs[2][SLOTS * 8];  // 2 x 19584 B

  const int tid = threadIdx.x;
  const int b = blockIdx.z, by = blockIdx.y, bx = blockIdx.x;
  const int lane = tid & 63, w = tid >> 6;
  const int r = lane & 15, g = lane >> 4;       // g in 0..3
  const int g1 = g >> 1, hh16 = (g & 1) * 16;
  const char* xtb = (const char*)xt + (size_t)b * 2097152;  // b-plane (4 cg)
  const int grow0 = by * 16 - 1, gcol0 = bx * 32 - 1;

  // source offsets: dest slot s (linear) -> inverse-swizzle -> (p,hh) -> x_t
  int srcoff[5];
#pragma unroll
  for (int j = 0; j < 5; ++j) {
    int s = tid + j * 256;
    int L = s << 4;
    int f = (L >> 7) & 7;
    int orig = L ^ (f << 4);
    int p = orig >> 5, hh = (orig >> 4) & 1;
    int rr = p / 34, cc = p - rr * 34;
    int gr = grow0 + rr, gc = gcol0 + cc;
    bool inb = ((unsigned)gr < 128u) && ((unsigned)gc < 128u);
    srcoff[j] = inb ? ((gr * 128 + gc) * 32 + hh * 16) : -1;
  }

  // B-frag base: patch P = nt*16 + r -> pi = nt*2 + (r>>3), pj = r&7
  const int pbase = (r >> 3) * 136 + (r & 7) * 4 + g1;

  f32x4 acc[4];  // [parity*2 + nt]
#pragma unroll
  for (int t = 0; t < 4; ++t)
#pragma unroll
    for (int i = 0; i < 4; ++i) acc[t][i] = 0.f;
  short8 st[5];
  short8 af[18];

  auto AFLOAD = [&](int ch) {
    const short8* wv8 = (const short8*)WA;
    const int lc = ch * 256 + tid;
#pragma unroll
    for (int s = 0; s < 18; ++s) af[s] = wv8[s * 1024 + lc];
  };
  auto LOAD = [&](int cg) {
    const char* base = xtb + (size_t)cg * 524288;
#pragma unroll
    for (int j = 0; j < 5; ++j) {
      if (j < 4 || tid < SLOTS - 1024) {
        st[j] = (srcoff[j] >= 0) ? *(const short8*)(base + srcoff[j])
                                 : (short8)(short)0;
      }
    }
  };
  auto WRITE = [&](int buf) {
    char* lb = (char*)&xs[buf & 1][0];
#pragma unroll
    for (int j = 0; j < 5; ++j)
      if (j < 4 || tid < SLOTS - 1024)
        *(short8*)(lb + (tid + j * 256) * 16) = st[j];
  };
  auto MFMA = [&](int ch) {
    const char* base = (const char*)&xs[ch & 1][0];
#pragma unroll
    for (int s = 0; s < 18; ++s) {
      const int toff = ((2 * s) / 6) * 34 + (2 * s) % 6;  // compile-time
      int p = pbase + toff;
      int a0 = (p * 32) ^ (((p >> 2) & 7) << 4) ^ hh16;
      int a1 = (a0 + 8704) ^ 64;          // swz(p+272) identity
      short8 bv0 = *(const short8*)(base + a0);
      short8 bv1 = *(const short8*)(base + a1);
      const int q = (s & 1) * 2;
      acc[q + 0] = __builtin_amdgcn_mfma_f32_16x16x32_bf16(af[s], bv0, acc[q + 0], 0, 0, 0);
      acc[q + 1] = __builtin_amdgcn_mfma_f32_16x16x32_bf16(af[s], bv1, acc[q + 1], 0, 0, 0);
    }
  };

  LOAD(0);
  WRITE(0);
  __syncthreads();
#pragma unroll
  for (int c = 0; c < 4; ++c) {
    AFLOAD(c);                              // 18 L2 loads first (oldest in FIFO
    __builtin_amdgcn_sched_barrier(0);      //  -> af waits never drain staging)
    if (c < 3) LOAD(c + 1);                 // 5 coalesced short8 loads
    __builtin_amdgcn_sched_barrier(0);
    MFMA(c);
    if (c < 3) {
      WRITE(c + 1);                         // 5 linear ds_write_b128
      __syncthreads();
    }
  }

  // epilogue: D col = lane&15 = r -> patch P = nt*16+r; row = g*4+reg -> o
#pragma unroll
  for (int nt = 0; nt < 2; ++nt) {
    const int P = nt * 16 + r;
    const int pig = by * 4 + (P >> 3), pjg = bx * 8 + (P & 7);
    const int icl = (pig == 0) ? 0 : ((pig == 31) ? 2 : 1);
    const int jcl = (pjg == 0) ? 0 : ((pjg == 31) ? 2 : 1);
    const float* offr = offC + (icl * 3 + jcl) * 64;
    float* ob = out + (((size_t)b * 64) * NP + pig) * NP + pjg;
#pragma unroll
    for (int reg = 0; reg < 4; ++reg) {
      const int o = w * 16 + g * 4 + reg;
      float v = acc[nt][reg] + acc[2 + nt][reg];
      ob[(size_t)o * 1024] = v + offr[o];
    }
  }
}

extern "C" void kernel_launch(void* const* d_in, const int* in_sizes, int n_in,
                              void* d_out, int out_size, void* d_ws, size_t ws_size,
                              hipStream_t stream) {
  const float* x     = (const float*)d_in[0];
  const float* g0    = (const float*)d_in[1];
  const float* b0    = (const float*)d_in[2];
  const float* m0    = (const float*)d_in[3];
  const float* v0    = (const float*)d_in[4];
  const float* wv    = (const float*)d_in[15];
  const float* bv    = (const float*)d_in[16];
  const float* alpha = (const float*)d_in[17];
  float* out = (float*)d_out;

  unsigned short* WA = (unsigned short*)d_ws;              // 288 KB at offset 0
  float* offC = (float*)((char*)d_ws + 294912);            // 9*64 floats
  unsigned short* xt = (unsigned short*)((char*)d_ws + 524288);  // 32 MiB

  k_pc<<<4113, 256, 0, stream>>>(x, wv, g0, b0, m0, v0, bv, alpha, WA, offC, xt);
  dim3 grid(NP / 8, NP / 4, Bn);
  k_conv<<<grid, 256, 0, stream>>>(xt, WA, offC, out);
}